// Round 4
// baseline (355.815 us; speedup 1.0000x reference)
//
#include <hip/hip_runtime.h>

#define N_NODES 100000
#define N_EDGES 1600000
#define D_IN    256
#define D_OUT   128

// ---------------------------------------------------------------------------
// Kernel 1: h[N, D_OUT] = x[N, D_IN] @ W[D_OUT, D_IN]^T + b
// fp32 vector-ALU GEMM (no fp32 MFMA on CDNA4).
// BM=64 rows, BN=128 (= all cols), BK=32. 256 threads.
// Per-thread micro-tile: 8 rows x 4 cols (acc[8][4]).
//   cg = tid & 31  -> cols cg*4 .. cg*4+3
//   rg = tid >> 5  -> rows rg*8 .. rg*8+7
// LDS: xs[64][36] (pad 4 keeps float4 alignment, spreads write banks)
//      Ws[32][132] k-major so the col-read is contiguous b128 across lanes
// ---------------------------------------------------------------------------
__global__ __launch_bounds__(256) void gcn_linear_kernel(
    const float* __restrict__ x, const float* __restrict__ W,
    const float* __restrict__ b, float* __restrict__ h) {
  constexpr int BM = 64, BK = 32;
  __shared__ float xs[BM][BK + 4];     // 9216 B
  __shared__ float Ws[BK][D_OUT + 4];  // 16896 B

  const int tid = threadIdx.x;
  const int gm0 = blockIdx.x * BM;
  const int cg = tid & 31;   // col group
  const int rg = tid >> 5;   // row group

  float acc[8][4];
#pragma unroll
  for (int i = 0; i < 8; ++i)
#pragma unroll
    for (int j = 0; j < 4; ++j) acc[i][j] = 0.f;

  for (int kk = 0; kk < D_IN; kk += BK) {
    // ---- stage x tile: 64 rows x 32 k = 512 float4, 2 per thread ----
#pragma unroll
    for (int q = 0; q < 2; ++q) {
      int idx = tid + q * 256;        // 0..511
      int row = idx >> 3;             // 0..63
      int kq  = (idx & 7) << 2;       // 0,4,..,28
      int gr  = gm0 + row;
      gr = gr < N_NODES ? gr : N_NODES - 1;   // clamp; OOB rows never stored
      float4 v = *(const float4*)&x[(size_t)gr * D_IN + kk + kq];
      *(float4*)&xs[row][kq] = v;
    }
    // ---- stage W tile: 128 cols x 32 k = 1024 float4, 4 per thread ----
#pragma unroll
    for (int q = 0; q < 4; ++q) {
      int idx = tid + q * 256;        // 0..1023
      int col = idx >> 3;             // 0..127
      int kq  = (idx & 7) << 2;       // 0,4,..,28
      float4 v = *(const float4*)&W[col * D_IN + kk + kq];
      Ws[kq + 0][col] = v.x;
      Ws[kq + 1][col] = v.y;
      Ws[kq + 2][col] = v.z;
      Ws[kq + 3][col] = v.w;
    }
    __syncthreads();

#pragma unroll
    for (int k = 0; k < BK; k += 4) {
      float4 w0 = *(const float4*)&Ws[k + 0][cg << 2];
      float4 w1 = *(const float4*)&Ws[k + 1][cg << 2];
      float4 w2 = *(const float4*)&Ws[k + 2][cg << 2];
      float4 w3 = *(const float4*)&Ws[k + 3][cg << 2];
#pragma unroll
      for (int i = 0; i < 8; ++i) {
        float4 a = *(const float4*)&xs[(rg << 3) + i][k];
        acc[i][0] += a.x * w0.x + a.y * w1.x + a.z * w2.x + a.w * w3.x;
        acc[i][1] += a.x * w0.y + a.y * w1.y + a.z * w2.y + a.w * w3.y;
        acc[i][2] += a.x * w0.z + a.y * w1.z + a.z * w2.z + a.w * w3.z;
        acc[i][3] += a.x * w0.w + a.y * w1.w + a.z * w2.w + a.w * w3.w;
      }
    }
    __syncthreads();
  }

  // ---- epilogue: + bias, float4 store ----
  float4 bb = *(const float4*)&b[cg << 2];
#pragma unroll
  for (int i = 0; i < 8; ++i) {
    int gr = gm0 + (rg << 3) + i;
    if (gr < N_NODES) {
      float4 o;
      o.x = acc[i][0] + bb.x;
      o.y = acc[i][1] + bb.y;
      o.z = acc[i][2] + bb.z;
      o.w = acc[i][3] + bb.w;
      *(float4*)&h[(size_t)gr * D_OUT + (cg << 2)] = o;
    }
  }
}

// ---------------------------------------------------------------------------
// Kernel 2: row_ptr[v] = lower_bound(dst, v) over sorted dst (CSR offsets).
// ---------------------------------------------------------------------------
__global__ __launch_bounds__(256) void gcn_rowptr_kernel(
    const int* __restrict__ dst, int* __restrict__ row_ptr) {
  int v = blockIdx.x * blockDim.x + threadIdx.x;
  if (v > N_NODES) return;
  int lo = 0, hi = N_EDGES;
  while (lo < hi) {
    int mid = (lo + hi) >> 1;
    if (dst[mid] < v) lo = mid + 1; else hi = mid;
  }
  row_ptr[v] = lo;
}

// ---------------------------------------------------------------------------
// Kernel 3: out[v][t] = sum_{e in [row_ptr[v], row_ptr[v+1])} h[src[e]][t]*w[e]
// One block per node, 128 threads = one output dim each. Atomic-free,
// deterministic. h gather is 512 B/edge coalesced; h fits L3 (51.2 MB).
// ---------------------------------------------------------------------------
__global__ __launch_bounds__(128) void gcn_agg_kernel(
    const float* __restrict__ h, const int* __restrict__ src,
    const float* __restrict__ w, const int* __restrict__ row_ptr,
    float* __restrict__ out) {
  const int v = blockIdx.x;
  const int t = threadIdx.x;
  const int s = row_ptr[v];
  const int e = row_ptr[v + 1];
  float acc = 0.f;
  for (int i = s; i < e; ++i) {
    int   sv = src[i];        // wave-uniform
    float wv = w[i];          // wave-uniform
    acc += h[sv * D_OUT + t] * wv;
  }
  out[v * D_OUT + t] = acc;
}

extern "C" void kernel_launch(void* const* d_in, const int* in_sizes, int n_in,
                              void* d_out, int out_size, void* d_ws, size_t ws_size,
                              hipStream_t stream) {
  const float* x   = (const float*)d_in[0];
  const int*   src = (const int*)d_in[1];
  const int*   dst = (const int*)d_in[2];
  const float* w   = (const float*)d_in[3];
  const float* W   = (const float*)d_in[4];
  const float* b   = (const float*)d_in[5];
  float* out = (float*)d_out;

  // workspace layout: h (51.2 MB) | row_ptr (400 KB)
  float* h = (float*)d_ws;
  int* row_ptr = (int*)((char*)d_ws + (size_t)N_NODES * D_OUT * sizeof(float));

  // 1) h = x @ W^T + b
  {
    dim3 grid((N_NODES + 63) / 64);
    gcn_linear_kernel<<<grid, 256, 0, stream>>>(x, W, b, h);
  }
  // 2) CSR offsets from sorted dst
  {
    dim3 grid((N_NODES + 1 + 255) / 256);
    gcn_rowptr_kernel<<<grid, 256, 0, stream>>>(dst, row_ptr);
  }
  // 3) segment-sum of w-scaled gathered rows
  {
    gcn_agg_kernel<<<N_NODES, 128, 0, stream>>>(h, src, w, row_ptr, out);
  }
}

// Round 5
// 126.586 us; speedup vs baseline: 2.8108x; 2.8108x over previous
//
#include <hip/hip_runtime.h>

#define N_NODES 100000
#define N_EDGES 1600000
#define D_IN    256
#define D_OUT   128

typedef __attribute__((ext_vector_type(8))) short          bf16x8;
typedef __attribute__((ext_vector_type(8))) unsigned short ushort8;
typedef __attribute__((ext_vector_type(4))) float          f32x4;

// f32 -> bf16 (round-to-nearest-even), as raw ushort
__device__ inline unsigned short f2bf(float f) {
  union { float f; unsigned u; } v; v.f = f;
  unsigned r = v.u + 0x7fffu + ((v.u >> 16) & 1u);
  return (unsigned short)(r >> 16);
}
__device__ inline float bf2f(unsigned short u) {
  union { unsigned u; float f; } v; v.u = ((unsigned)u) << 16;
  return v.f;
}

// ---------------------------------------------------------------------------
// Kernel 0: pack W[D_OUT][D_IN] f32 -> bf16 MFMA B-fragment order.
// Frag f = (n*8 + s)*64 + lane holds B[k = s*32+(lane>>4)*8 + j][col = n*16+(lane&15)]
//        = W[col][k], j = 0..7.  One wave's frag loads = 1 KB contiguous.
// ---------------------------------------------------------------------------
__global__ __launch_bounds__(256) void gcn_packW_kernel(
    const float* __restrict__ W, unsigned short* __restrict__ Wp) {
  int f = blockIdx.x * blockDim.x + threadIdx.x;   // 0..4095
  if (f >= 4096) return;
  int n = f >> 9, s = (f >> 6) & 7, lane = f & 63;
  int col = n * 16 + (lane & 15);
  int k0  = s * 32 + (lane >> 4) * 8;
#pragma unroll
  for (int j = 0; j < 8; ++j)
    Wp[f * 8 + j] = f2bf(W[col * D_IN + k0 + j]);
}

// ---------------------------------------------------------------------------
// Kernel 1: h[N, D_OUT] (bf16) = bf16(x) @ W^T + b via mfma_f32_16x16x32_bf16.
// No LDS: A-frags straight from global x (f32 -> bf16 in regs), B-frags from
// the L2-resident 64 KB pack. 4 waves/block, 16 rows/wave -> 64 rows/block.
// A layout: lane holds A[row=lane&15][k=(lane>>4)*8 + j].
// C layout: lane holds D[row=(lane>>4)*4 + i][col=lane&15] (m89-verified).
// ---------------------------------------------------------------------------
__global__ __launch_bounds__(256) void gcn_linear_mfma_kernel(
    const float* __restrict__ x, const unsigned short* __restrict__ Wp,
    const float* __restrict__ b, unsigned short* __restrict__ h) {
  const int lane = threadIdx.x & 63;
  const int wv   = threadIdx.x >> 6;
  const int r0   = blockIdx.x * 64 + wv * 16;

  int arow = r0 + (lane & 15);
  arow = arow < N_NODES ? arow : N_NODES - 1;      // clamp; OOB rows never stored
  const int kg = (lane >> 4) * 8;
  const float* xrow = x + (size_t)arow * D_IN + kg;

  f32x4 acc[8];
#pragma unroll
  for (int n = 0; n < 8; ++n) acc[n] = (f32x4){0.f, 0.f, 0.f, 0.f};

#pragma unroll
  for (int s = 0; s < 8; ++s) {
    float4 a0 = *(const float4*)(xrow + s * 32);
    float4 a1 = *(const float4*)(xrow + s * 32 + 4);
    bf16x8 af;
    af[0] = (short)f2bf(a0.x); af[1] = (short)f2bf(a0.y);
    af[2] = (short)f2bf(a0.z); af[3] = (short)f2bf(a0.w);
    af[4] = (short)f2bf(a1.x); af[5] = (short)f2bf(a1.y);
    af[6] = (short)f2bf(a1.z); af[7] = (short)f2bf(a1.w);
#pragma unroll
    for (int n = 0; n < 8; ++n) {
      bf16x8 bfrag = *(const bf16x8*)(Wp + ((size_t)((n * 8 + s) * 64 + lane) * 8));
      acc[n] = __builtin_amdgcn_mfma_f32_16x16x32_bf16(af, bfrag, acc[n], 0, 0, 0);
    }
  }

  // epilogue: + bias, bf16 store
  const int orow0 = r0 + (lane >> 4) * 4;
  const int col0  = lane & 15;
#pragma unroll
  for (int n = 0; n < 8; ++n) {
    const int col = n * 16 + col0;
    const float bias = b[col];
#pragma unroll
    for (int i = 0; i < 4; ++i) {
      const int row = orow0 + i;
      if (row < N_NODES)
        h[(size_t)row * D_OUT + col] = f2bf(acc[n][i] + bias);
    }
  }
}

// ---------------------------------------------------------------------------
// Kernel 2: row_ptr[v] = lower_bound(dst, v) over sorted dst (CSR offsets).
// ---------------------------------------------------------------------------
__global__ __launch_bounds__(256) void gcn_rowptr_kernel(
    const int* __restrict__ dst, int* __restrict__ row_ptr) {
  int v = blockIdx.x * blockDim.x + threadIdx.x;
  if (v > N_NODES) return;
  int lo = 0, hi = N_EDGES;
  while (lo < hi) {
    int mid = (lo + hi) >> 1;
    if (dst[mid] < v) lo = mid + 1; else hi = mid;
  }
  row_ptr[v] = lo;
}

// ---------------------------------------------------------------------------
// Kernel 3: out[v][:] = sum_e h[src[e]][:] * w[e].  One WAVE per node:
// 4 edges in flight (groups g=0..3), 16 lanes/group x 16 B (8 bf16) = the
// full 256 B row per edge. shfl_xor(16,32) cross-group reduce, float4 store.
// Atomic-free, deterministic.
// ---------------------------------------------------------------------------
__global__ __launch_bounds__(256) void gcn_agg_kernel(
    const unsigned short* __restrict__ h, const int* __restrict__ src,
    const float* __restrict__ w, const int* __restrict__ rp,
    float* __restrict__ out) {
  const int node = (blockIdx.x << 2) + (threadIdx.x >> 6);
  if (node >= N_NODES) return;
  const int lane = threadIdx.x & 63;
  const int g  = lane >> 4;          // edge slot 0..3
  const int dg = (lane & 15) << 3;   // dim offset 0,8,...,120

  const int s = rp[node], e = rp[node + 1];
  float acc[8];
#pragma unroll
  for (int j = 0; j < 8; ++j) acc[j] = 0.f;

  for (int i = s + g; i < e; i += 4) {
    const int   sv = src[i];         // group-uniform (broadcast load)
    const float wv = w[i];
    ushort8 hv = *(const ushort8*)(h + (size_t)sv * D_OUT + dg);
#pragma unroll
    for (int j = 0; j < 8; ++j) acc[j] += bf2f(hv[j]) * wv;
  }
#pragma unroll
  for (int j = 0; j < 8; ++j) acc[j] += __shfl_xor(acc[j], 16);
#pragma unroll
  for (int j = 0; j < 8; ++j) acc[j] += __shfl_xor(acc[j], 32);

  if (g == 0) {
    float4 o0 = {acc[0], acc[1], acc[2], acc[3]};
    float4 o1 = {acc[4], acc[5], acc[6], acc[7]};
    float* op = out + (size_t)node * D_OUT + dg;
    *(float4*)(op)     = o0;
    *(float4*)(op + 4) = o1;
  }
}

extern "C" void kernel_launch(void* const* d_in, const int* in_sizes, int n_in,
                              void* d_out, int out_size, void* d_ws, size_t ws_size,
                              hipStream_t stream) {
  const float* x   = (const float*)d_in[0];
  const int*   src = (const int*)d_in[1];
  const int*   dst = (const int*)d_in[2];
  const float* w   = (const float*)d_in[3];
  const float* W   = (const float*)d_in[4];
  const float* b   = (const float*)d_in[5];
  float* out = (float*)d_out;

  // workspace: Wpack (64 KB) | h bf16 (25.6 MB) | row_ptr (400 KB)
  unsigned short* Wp = (unsigned short*)d_ws;
  unsigned short* h  = (unsigned short*)((char*)d_ws + 65536);
  int* row_ptr = (int*)((char*)d_ws + 65536 + (size_t)N_NODES * D_OUT * sizeof(unsigned short));

  // 0) pack W -> bf16 fragment order
  gcn_packW_kernel<<<16, 256, 0, stream>>>(W, Wp);
  // 1) h = bf16(x @ W^T + b)
  gcn_linear_mfma_kernel<<<(N_NODES + 63) / 64, 256, 0, stream>>>(x, Wp, b, h);
  // 2) CSR offsets from sorted dst
  gcn_rowptr_kernel<<<(N_NODES + 1 + 255) / 256, 256, 0, stream>>>(dst, row_ptr);
  // 3) segment-sum of w-scaled gathered rows
  gcn_agg_kernel<<<N_NODES / 4, 256, 0, stream>>>(h, src, w, row_ptr, out);
}

// Round 6
// 122.540 us; speedup vs baseline: 2.9037x; 1.0330x over previous
//
#include <hip/hip_runtime.h>

#define N_NODES 100000
#define N_EDGES 1600000
#define D_IN    256
#define D_OUT   128

typedef __attribute__((ext_vector_type(8))) short          bf16x8;
typedef __attribute__((ext_vector_type(8))) unsigned short ushort8;
typedef __attribute__((ext_vector_type(4))) float          f32x4;

// f32 -> bf16 (round-to-nearest-even), as raw ushort
__device__ inline unsigned short f2bf(float f) {
  union { float f; unsigned u; } v; v.f = f;
  unsigned r = v.u + 0x7fffu + ((v.u >> 16) & 1u);
  return (unsigned short)(r >> 16);
}
__device__ inline float bf2f(unsigned short u) {
  union { unsigned u; float f; } v; v.u = ((unsigned)u) << 16;
  return v.f;
}

// ---------------------------------------------------------------------------
// Kernel 0: pack W[D_OUT][D_IN] f32 -> bf16 MFMA B-fragment order.
// Frag f = (n*8 + s)*64 + lane holds B[k = s*32+(lane>>4)*8 + j][col = n*16+(lane&15)]
//        = W[col][k], j = 0..7.  (Layout verified correct in round 4.)
// ---------------------------------------------------------------------------
__global__ __launch_bounds__(256) void gcn_packW_kernel(
    const float* __restrict__ W, unsigned short* __restrict__ Wp) {
  int f = blockIdx.x * blockDim.x + threadIdx.x;   // 0..4095
  if (f >= 4096) return;
  int n = f >> 9, s = (f >> 6) & 7, lane = f & 63;
  int col = n * 16 + (lane & 15);
  int k0  = s * 32 + (lane >> 4) * 8;
#pragma unroll
  for (int j = 0; j < 8; ++j)
    Wp[f * 8 + j] = f2bf(W[col * D_IN + k0 + j]);
}

// ---------------------------------------------------------------------------
// Kernel 1: h[N, D_OUT] (bf16) = bf16(x) @ W^T + b via mfma_f32_16x16x32_bf16.
// 32 rows per wave (two A-frags share each B-frag load -> half the L2 B
// traffic, 2 MFMA per B load, 2x x-stream MLP). 4 waves/block = 128 rows.
// A layout: lane holds A[row=lane&15][k=(lane>>4)*8 + j].
// C layout: lane holds D[row=(lane>>4)*4 + i][col=lane&15].
// ---------------------------------------------------------------------------
__global__ __launch_bounds__(256) void gcn_linear_mfma_kernel(
    const float* __restrict__ x, const unsigned short* __restrict__ Wp,
    const float* __restrict__ b, unsigned short* __restrict__ h) {
  const int lane = threadIdx.x & 63;
  const int wid  = threadIdx.x >> 6;
  const int r0   = blockIdx.x * 128 + wid * 32;

  int arow0 = r0 + (lane & 15);
  int arow1 = r0 + 16 + (lane & 15);
  arow0 = arow0 < N_NODES ? arow0 : N_NODES - 1;   // clamp; OOB rows never stored
  arow1 = arow1 < N_NODES ? arow1 : N_NODES - 1;
  const int kg = (lane >> 4) * 8;
  const float* xr0 = x + (size_t)arow0 * D_IN + kg;
  const float* xr1 = x + (size_t)arow1 * D_IN + kg;

  f32x4 acc0[8], acc1[8];
#pragma unroll
  for (int n = 0; n < 8; ++n) {
    acc0[n] = (f32x4){0.f, 0.f, 0.f, 0.f};
    acc1[n] = (f32x4){0.f, 0.f, 0.f, 0.f};
  }

#pragma unroll
  for (int s = 0; s < 8; ++s) {
    float4 a00 = *(const float4*)(xr0 + s * 32);
    float4 a01 = *(const float4*)(xr0 + s * 32 + 4);
    float4 a10 = *(const float4*)(xr1 + s * 32);
    float4 a11 = *(const float4*)(xr1 + s * 32 + 4);
    bf16x8 af0, af1;
    af0[0] = (short)f2bf(a00.x); af0[1] = (short)f2bf(a00.y);
    af0[2] = (short)f2bf(a00.z); af0[3] = (short)f2bf(a00.w);
    af0[4] = (short)f2bf(a01.x); af0[5] = (short)f2bf(a01.y);
    af0[6] = (short)f2bf(a01.z); af0[7] = (short)f2bf(a01.w);
    af1[0] = (short)f2bf(a10.x); af1[1] = (short)f2bf(a10.y);
    af1[2] = (short)f2bf(a10.z); af1[3] = (short)f2bf(a10.w);
    af1[4] = (short)f2bf(a11.x); af1[5] = (short)f2bf(a11.y);
    af1[6] = (short)f2bf(a11.z); af1[7] = (short)f2bf(a11.w);
#pragma unroll
    for (int n = 0; n < 8; ++n) {
      bf16x8 bfrag = *(const bf16x8*)(Wp + ((size_t)((n * 8 + s) * 64 + lane) * 8));
      acc0[n] = __builtin_amdgcn_mfma_f32_16x16x32_bf16(af0, bfrag, acc0[n], 0, 0, 0);
      acc1[n] = __builtin_amdgcn_mfma_f32_16x16x32_bf16(af1, bfrag, acc1[n], 0, 0, 0);
    }
  }

  // epilogue: + bias, bf16 store (both 16-row halves)
  const int col0 = lane & 15;
  const int q4   = (lane >> 4) * 4;
#pragma unroll
  for (int n = 0; n < 8; ++n) {
    const int col = n * 16 + col0;
    const float bias = b[col];
#pragma unroll
    for (int i = 0; i < 4; ++i) {
      const int row0 = r0 + q4 + i;
      const int row1 = r0 + 16 + q4 + i;
      if (row0 < N_NODES)
        h[(size_t)row0 * D_OUT + col] = f2bf(acc0[n][i] + bias);
      if (row1 < N_NODES)
        h[(size_t)row1 * D_OUT + col] = f2bf(acc1[n][i] + bias);
    }
  }
}

// ---------------------------------------------------------------------------
// Kernel 2: row_ptr[v] = lower_bound(dst, v) over sorted dst (CSR offsets).
// ---------------------------------------------------------------------------
__global__ __launch_bounds__(256) void gcn_rowptr_kernel(
    const int* __restrict__ dst, int* __restrict__ row_ptr) {
  int v = blockIdx.x * blockDim.x + threadIdx.x;
  if (v > N_NODES) return;
  int lo = 0, hi = N_EDGES;
  while (lo < hi) {
    int mid = (lo + hi) >> 1;
    if (dst[mid] < v) lo = mid + 1; else hi = mid;
  }
  row_ptr[v] = lo;
}

// ---------------------------------------------------------------------------
// Kernel 3: out[v][:] = sum_e h[src[e]][:] * w[e].  One WAVE per node,
// 4 lane-groups x 16 lanes. Each group takes 4 edges per iteration
// (16 edges/wave/iter = mean degree): predicated (src,w) preload, then
// 4 INDEPENDENT 16 B gathers issued back-to-back (16 outstanding/wave),
// then accumulate. shfl_xor(16,32) cross-group reduce, float4 store.
// Atomic-free, deterministic.
// ---------------------------------------------------------------------------
__global__ __launch_bounds__(256) void gcn_agg_kernel(
    const unsigned short* __restrict__ h, const int* __restrict__ src,
    const float* __restrict__ w, const int* __restrict__ rp,
    float* __restrict__ out) {
  const int node = (blockIdx.x << 2) + (threadIdx.x >> 6);
  if (node >= N_NODES) return;
  const int lane = threadIdx.x & 63;
  const int g  = lane >> 4;          // group 0..3
  const int dg = (lane & 15) << 3;   // dim offset 0,8,...,120

  const int s = rp[node], e = rp[node + 1];
  float acc[8];
#pragma unroll
  for (int j = 0; j < 8; ++j) acc[j] = 0.f;

  for (int base = s; base < e; base += 16) {
    const int i0 = base + (g << 2);      // group-uniform
    if (i0 < e) {
      int   sv[4];
      float wv[4];
#pragma unroll
      for (int j = 0; j < 4; ++j) {
        int  i = i0 + j;
        bool valid = (i < e);
        int  ic = valid ? i : i0;        // i0 is valid here
        sv[j] = src[ic];
        wv[j] = valid ? w[ic] : 0.f;
      }
      ushort8 hv[4];
#pragma unroll
      for (int j = 0; j < 4; ++j)
        hv[j] = *(const ushort8*)(h + (size_t)sv[j] * D_OUT + dg);
#pragma unroll
      for (int j = 0; j < 4; ++j)
#pragma unroll
        for (int k = 0; k < 8; ++k)
          acc[k] += bf2f(hv[j][k]) * wv[j];
    }
  }

#pragma unroll
  for (int j = 0; j < 8; ++j) acc[j] += __shfl_xor(acc[j], 16);
#pragma unroll
  for (int j = 0; j < 8; ++j) acc[j] += __shfl_xor(acc[j], 32);

  if (g == 0) {
    float4 o0 = {acc[0], acc[1], acc[2], acc[3]};
    float4 o1 = {acc[4], acc[5], acc[6], acc[7]};
    float* op = out + (size_t)node * D_OUT + dg;
    *(float4*)(op)     = o0;
    *(float4*)(op + 4) = o1;
  }
}

extern "C" void kernel_launch(void* const* d_in, const int* in_sizes, int n_in,
                              void* d_out, int out_size, void* d_ws, size_t ws_size,
                              hipStream_t stream) {
  const float* x   = (const float*)d_in[0];
  const int*   src = (const int*)d_in[1];
  const int*   dst = (const int*)d_in[2];
  const float* w   = (const float*)d_in[3];
  const float* W   = (const float*)d_in[4];
  const float* b   = (const float*)d_in[5];
  float* out = (float*)d_out;

  // workspace: Wpack (64 KB) | h bf16 (25.6 MB) | row_ptr (400 KB)
  unsigned short* Wp = (unsigned short*)d_ws;
  unsigned short* h  = (unsigned short*)((char*)d_ws + 65536);
  int* row_ptr = (int*)((char*)d_ws + 65536 + (size_t)N_NODES * D_OUT * sizeof(unsigned short));

  // 0) pack W -> bf16 fragment order
  gcn_packW_kernel<<<16, 256, 0, stream>>>(W, Wp);
  // 1) h = bf16(x @ W^T + b), 128 rows/block
  gcn_linear_mfma_kernel<<<(N_NODES + 127) / 128, 256, 0, stream>>>(x, Wp, b, h);
  // 2) CSR offsets from sorted dst
  gcn_rowptr_kernel<<<(N_NODES + 1 + 255) / 256, 256, 0, stream>>>(dst, row_ptr);
  // 3) segment-sum of w-scaled gathered rows
  gcn_agg_kernel<<<N_NODES / 4, 256, 0, stream>>>(h, src, w, row_ptr, out);
}